// Round 1
// baseline (883.480 us; speedup 1.0000x reference)
//
#include <hip/hip_runtime.h>
#include <cstdint>

#define N_NODES 50000
#define N_EDGES 800000
#define N_FEAT 256
#define HIDDEN 128
#define N_CLASSES 40

// ---------------- degree / normalization ----------------

__global__ void count_deg(const int* __restrict__ dst, int* __restrict__ deg) {
    int e = blockIdx.x * 256 + threadIdx.x;
    if (e < N_EDGES) atomicAdd(&deg[dst[e]], 1);
}

__global__ void calc_dinv(const int* __restrict__ deg, float* __restrict__ dinv) {
    int i = blockIdx.x * 256 + threadIdx.x;
    if (i < N_NODES) dinv[i] = rsqrtf((float)(deg[i] + 1));  // +1 self-loop
}

__global__ void calc_norm(const int* __restrict__ src, const int* __restrict__ dst,
                          const float* __restrict__ dinv, float* __restrict__ norm) {
    int e = blockIdx.x * 256 + threadIdx.x;
    if (e < N_EDGES) norm[e] = dinv[src[e]] * dinv[dst[e]];
}

// ---------------- GEMM 1: h1[N,128] = x[N,256] @ W1[256,128] ----------------
// block = 256 threads = 2 rows x 128 cols; x rows staged in LDS, W1 from L2.

__global__ void gemm1(const float* __restrict__ x, const float* __restrict__ W,
                      float* __restrict__ h) {
    __shared__ float xs[2][N_FEAT];
    int t = threadIdx.x;
    int col = t & 127;
    int r = t >> 7;
    int row0 = blockIdx.x * 2;
    for (int i = t; i < 2 * N_FEAT; i += 256)
        xs[i >> 8][i & 255] = x[(size_t)(row0 + (i >> 8)) * N_FEAT + (i & 255)];
    __syncthreads();
    float acc = 0.f;
#pragma unroll 8
    for (int k = 0; k < N_FEAT; ++k)
        acc = fmaf(xs[r][k], W[k * HIDDEN + col], acc);
    h[(size_t)(row0 + r) * HIDDEN + col] = acc;
}

// ---------------- edge scatter, layer 1 (128 feats) ----------------
// one thread per (edge, feat); 128 consecutive threads share an edge.

__global__ void agg1(const int* __restrict__ src, const int* __restrict__ dst,
                     const float* __restrict__ norm, const float* __restrict__ h1,
                     float* __restrict__ hag) {
    int idx = blockIdx.x * 256 + threadIdx.x;   // < E*128 = 102.4M, fits int
    int e = idx >> 7;
    if (e >= N_EDGES) return;
    int f = idx & 127;
    float v = h1[(size_t)src[e] * HIDDEN + f] * norm[e];
    atomicAdd(&hag[(size_t)dst[e] * HIDDEN + f], v);
}

// finalize layer 1: add self-loop + bias, ReLU (in place on hag)
__global__ void finalize1(float* __restrict__ hag, const float* __restrict__ h1,
                          const float* __restrict__ dinv, const float* __restrict__ b1) {
    int idx = blockIdx.x * 256 + threadIdx.x;  // N*128
    if (idx >= N_NODES * HIDDEN) return;
    int v = idx >> 7, f = idx & 127;
    float di = dinv[v];
    float val = hag[idx] + h1[idx] * di * di + b1[f];
    hag[idx] = val > 0.f ? val : 0.f;
}

// ---------------- GEMM 2: h2[N,40] = hag[N,128] @ W2[128,40] ----------------
// block = 256 = 4 waves; wave w computes row (blockIdx*4+w), lane<40 = class col.

__global__ void gemm2(const float* __restrict__ hag, const float* __restrict__ W2,
                      float* __restrict__ h2) {
    __shared__ float Ws[HIDDEN * N_CLASSES];  // 20 KB
    __shared__ float rs[4][HIDDEN];
    int t = threadIdx.x;
    for (int i = t; i < HIDDEN * N_CLASSES; i += 256) Ws[i] = W2[i];
    int row0 = blockIdx.x * 4;
    for (int i = t; i < 4 * HIDDEN; i += 256)
        rs[i >> 7][i & 127] = hag[(size_t)(row0 + (i >> 7)) * HIDDEN + (i & 127)];
    __syncthreads();
    int lane = t & 63, w = t >> 6;
    if (lane >= N_CLASSES) return;
    float acc = 0.f;
#pragma unroll 8
    for (int k = 0; k < HIDDEN; ++k)
        acc = fmaf(rs[w][k], Ws[k * N_CLASSES + lane], acc);
    h2[(size_t)(row0 + w) * N_CLASSES + lane] = acc;
}

// ---------------- edge scatter, layer 2 (40 feats) ----------------
// 64 threads (one wave) per edge, lanes 0..39 active.

__global__ void agg2(const int* __restrict__ src, const int* __restrict__ dst,
                     const float* __restrict__ norm, const float* __restrict__ h2,
                     float* __restrict__ oag) {
    int idx = blockIdx.x * 256 + threadIdx.x;   // < E*64 = 51.2M
    int e = idx >> 6;
    if (e >= N_EDGES) return;
    int f = idx & 63;
    if (f >= N_CLASSES) return;
    float v = h2[(size_t)src[e] * N_CLASSES + f] * norm[e];
    atomicAdd(&oag[(size_t)dst[e] * N_CLASSES + f], v);
}

// ---------------- finalize layer 2 + log_softmax (in place on out) ----------------
// one wave per node; lane<40 holds the class value.

__global__ void fin_lsm(float* __restrict__ out, const float* __restrict__ h2,
                        const float* __restrict__ dinv, const float* __restrict__ b2) {
    int lane = threadIdx.x & 63;
    int w = threadIdx.x >> 6;
    int v = blockIdx.x * 4 + w;
    if (v >= N_NODES) return;
    float val = -INFINITY;
    if (lane < N_CLASSES) {
        float di = dinv[v];
        val = out[(size_t)v * N_CLASSES + lane]
            + h2[(size_t)v * N_CLASSES + lane] * di * di + b2[lane];
    }
    float m = val;
#pragma unroll
    for (int off = 32; off; off >>= 1) m = fmaxf(m, __shfl_xor(m, off, 64));
    float e = (lane < N_CLASSES) ? expf(val - m) : 0.f;
    float s = e;
#pragma unroll
    for (int off = 32; off; off >>= 1) s += __shfl_xor(s, off, 64);
    if (lane < N_CLASSES)
        out[(size_t)v * N_CLASSES + lane] = val - m - logf(s);
}

// ---------------- launch ----------------

extern "C" void kernel_launch(void* const* d_in, const int* in_sizes, int n_in,
                              void* d_out, int out_size, void* d_ws, size_t ws_size,
                              hipStream_t stream) {
    const float* x  = (const float*)d_in[0];
    const int*   ei = (const int*)d_in[1];
    const float* W1 = (const float*)d_in[2];
    const float* b1 = (const float*)d_in[3];
    const float* W2 = (const float*)d_in[4];
    const float* b2 = (const float*)d_in[5];
    const int* src = ei;
    const int* dst = ei + N_EDGES;
    float* out = (float*)d_out;

    char* ws = (char*)d_ws;
    size_t off = 0;
    auto alloc = [&](size_t bytes) {
        void* p = ws + off;
        off += (bytes + 255) & ~(size_t)255;
        return p;
    };
    int*   deg  = (int*)alloc((size_t)N_NODES * 4);
    float* dinv = (float*)alloc((size_t)N_NODES * 4);
    float* norm = (float*)alloc((size_t)N_EDGES * 4);
    float* h1   = (float*)alloc((size_t)N_NODES * HIDDEN * 4);
    float* hag  = (float*)alloc((size_t)N_NODES * HIDDEN * 4);
    float* h2   = (float*)alloc((size_t)N_NODES * N_CLASSES * 4);

    hipMemsetAsync(deg, 0, (size_t)N_NODES * 4, stream);
    hipMemsetAsync(hag, 0, (size_t)N_NODES * HIDDEN * 4, stream);
    hipMemsetAsync(d_out, 0, (size_t)N_NODES * N_CLASSES * 4, stream);

    count_deg<<<(N_EDGES + 255) / 256, 256, 0, stream>>>(dst, deg);
    calc_dinv<<<(N_NODES + 255) / 256, 256, 0, stream>>>(deg, dinv);
    calc_norm<<<(N_EDGES + 255) / 256, 256, 0, stream>>>(src, dst, dinv, norm);

    gemm1<<<N_NODES / 2, 256, 0, stream>>>(x, W1, h1);
    agg1<<<(N_EDGES * (HIDDEN / 256) ) ? (N_EDGES / 2) : (N_EDGES / 2), 256, 0, stream>>>(src, dst, norm, h1, hag);
    // grid above: E*128/256 = E/2 = 400000 blocks
    finalize1<<<N_NODES * HIDDEN / 256, 256, 0, stream>>>(hag, h1, dinv, b1);

    gemm2<<<N_NODES / 4, 256, 0, stream>>>(hag, W2, h2);
    agg2<<<N_EDGES * 64 / 256, 256, 0, stream>>>(src, dst, norm, h2, out);
    fin_lsm<<<N_NODES / 4, 256, 0, stream>>>(out, h2, dinv, b2);
}

// Round 2
// 463.187 us; speedup vs baseline: 1.9074x; 1.9074x over previous
//
#include <hip/hip_runtime.h>
#include <cstdint>

#define N_NODES 50000
#define N_EDGES 800000
#define N_FEAT 256
#define HIDDEN 128
#define N_CLASSES 40
#define NB_NODES ((N_NODES + 255) / 256)   // 196 blocks for node-sized scans

// ---------------- degree / dinv ----------------

__global__ void count_deg(const int* __restrict__ dst, int* __restrict__ deg) {
    int e = blockIdx.x * 256 + threadIdx.x;
    if (e < N_EDGES) atomicAdd(&deg[dst[e]], 1);
}

__global__ void calc_dinv(const int* __restrict__ deg, float* __restrict__ dinv) {
    int i = blockIdx.x * 256 + threadIdx.x;
    if (i < N_NODES) dinv[i] = rsqrtf((float)(deg[i] + 1));  // +1 self-loop
}

// ---------------- exclusive scan of deg -> rowptr (3 small kernels) ----------------

__global__ void scan1(const int* __restrict__ deg, int* __restrict__ incl,
                      int* __restrict__ bsum) {
    __shared__ int s[256];
    int i = blockIdx.x * 256 + threadIdx.x;
    int v = (i < N_NODES) ? deg[i] : 0;
    s[threadIdx.x] = v;
    __syncthreads();
    for (int off = 1; off < 256; off <<= 1) {
        int t2 = 0;
        if (threadIdx.x >= off) t2 = s[threadIdx.x - off];
        __syncthreads();
        s[threadIdx.x] += t2;
        __syncthreads();
    }
    incl[i] = s[threadIdx.x];
    if (threadIdx.x == 255) bsum[blockIdx.x] = s[255];
}

__global__ void scan2(int* __restrict__ bsum) {  // in-place inclusive scan of NB_NODES sums
    __shared__ int s[256];
    int t = threadIdx.x;
    s[t] = (t < NB_NODES) ? bsum[t] : 0;
    __syncthreads();
    for (int off = 1; off < 256; off <<= 1) {
        int t2 = 0;
        if (t >= off) t2 = s[t - off];
        __syncthreads();
        s[t] += t2;
        __syncthreads();
    }
    if (t < NB_NODES) bsum[t] = s[t];
}

// rowptr[i] (exclusive) computed in place over incl[]
__global__ void scan3(int* __restrict__ incl, const int* __restrict__ deg,
                      const int* __restrict__ bsum) {
    int i = blockIdx.x * 256 + threadIdx.x;
    if (i >= N_NODES) return;
    int base = (blockIdx.x > 0) ? bsum[blockIdx.x - 1] : 0;
    incl[i] = incl[i] - deg[i] + base;  // exclusive offset
}

// ---------------- CSR fill: esrc sorted by dst ----------------

__global__ void fill_csr(const int* __restrict__ src, const int* __restrict__ dst,
                         const int* __restrict__ rowptr, int* __restrict__ cursor,
                         int* __restrict__ esrc) {
    int e = blockIdx.x * 256 + threadIdx.x;
    if (e >= N_EDGES) return;
    int d = dst[e];
    int p = rowptr[d] + atomicAdd(&cursor[d], 1);
    esrc[p] = src[e];
}

// ---------------- GEMM 1: h1[N,128] = x[N,256] @ W1[256,128] ----------------
// 8 rows/block, 256 threads; thread (col=t&127, rh=t>>7) computes 4 rows.

__global__ void gemm1(const float* __restrict__ x, const float* __restrict__ W,
                      float* __restrict__ h) {
    __shared__ float xs[8][N_FEAT];  // 8 KB
    int t = threadIdx.x;
    int row0 = blockIdx.x * 8;
    const float4* xv = (const float4*)(x + (size_t)row0 * N_FEAT);
    float4* xsv = (float4*)xs;
    for (int i = t; i < 8 * N_FEAT / 4; i += 256) xsv[i] = xv[i];
    __syncthreads();
    int col = t & 127, rh = t >> 7;  // rh uniform per wave
    float acc[4] = {0.f, 0.f, 0.f, 0.f};
#pragma unroll 4
    for (int k = 0; k < N_FEAT; ++k) {
        float w = W[k * HIDDEN + col];
#pragma unroll
        for (int j = 0; j < 4; ++j) acc[j] = fmaf(xs[rh * 4 + j][k], w, acc[j]);
    }
#pragma unroll
    for (int j = 0; j < 4; ++j)
        h[(size_t)(row0 + rh * 4 + j) * HIDDEN + col] = acc[j];
}

// ---------------- layer-1 aggregation: CSR gather + self-loop + bias + ReLU ----------------
// one wave per node; lane handles feats {2*lane, 2*lane+1} as float2.

__global__ void agg1_gather(const int* __restrict__ rowptr, const int* __restrict__ deg,
                            const int* __restrict__ esrc, const float* __restrict__ dinv,
                            const float* __restrict__ h1, const float* __restrict__ b1,
                            float* __restrict__ hag) {
    int w = threadIdx.x >> 6, lane = threadIdx.x & 63;
    int v = blockIdx.x * 4 + w;
    if (v >= N_NODES) return;
    int beg = rowptr[v], d = deg[v];
    float dv = dinv[v];
    float2 hv = ((const float2*)(h1 + (size_t)v * HIDDEN))[lane];
    float2 acc;
    acc.x = hv.x * dv * dv;
    acc.y = hv.y * dv * dv;
    for (int i = 0; i < d; ++i) {
        int s = esrc[beg + i];            // wave-uniform (scalar) load
        float wgt = dinv[s] * dv;         // wave-uniform
        float2 hs = ((const float2*)(h1 + (size_t)s * HIDDEN))[lane];
        acc.x = fmaf(hs.x, wgt, acc.x);
        acc.y = fmaf(hs.y, wgt, acc.y);
    }
    float2 bb = ((const float2*)b1)[lane];
    acc.x += bb.x; acc.y += bb.y;
    acc.x = acc.x > 0.f ? acc.x : 0.f;
    acc.y = acc.y > 0.f ? acc.y : 0.f;
    ((float2*)(hag + (size_t)v * HIDDEN))[lane] = acc;
}

// ---------------- GEMM 2: h2[N,40] = hag[N,128] @ W2[128,40] ----------------

__global__ void gemm2(const float* __restrict__ hag, const float* __restrict__ W2,
                      float* __restrict__ h2) {
    __shared__ float Ws[HIDDEN * N_CLASSES];  // 20 KB
    __shared__ float rs[4][HIDDEN];
    int t = threadIdx.x;
    for (int i = t; i < HIDDEN * N_CLASSES; i += 256) Ws[i] = W2[i];
    int row0 = blockIdx.x * 4;
    for (int i = t; i < 4 * HIDDEN; i += 256)
        rs[i >> 7][i & 127] = hag[(size_t)(row0 + (i >> 7)) * HIDDEN + (i & 127)];
    __syncthreads();
    int lane = t & 63, w = t >> 6;
    if (lane >= N_CLASSES) return;
    float acc = 0.f;
#pragma unroll 8
    for (int k = 0; k < HIDDEN; ++k)
        acc = fmaf(rs[w][k], Ws[k * N_CLASSES + lane], acc);
    h2[(size_t)(row0 + w) * N_CLASSES + lane] = acc;
}

// ---------------- layer-2 aggregation + bias + log_softmax ----------------
// one wave per node; lane < 40 holds the class value.

__global__ void agg2_lsm(const int* __restrict__ rowptr, const int* __restrict__ deg,
                         const int* __restrict__ esrc, const float* __restrict__ dinv,
                         const float* __restrict__ h2, const float* __restrict__ b2,
                         float* __restrict__ out) {
    int w = threadIdx.x >> 6, lane = threadIdx.x & 63;
    int v = blockIdx.x * 4 + w;
    if (v >= N_NODES) return;
    int beg = rowptr[v], d = deg[v];
    float dv = dinv[v];
    float val = 0.f;
    if (lane < N_CLASSES)
        val = h2[(size_t)v * N_CLASSES + lane] * dv * dv + b2[lane];
    for (int i = 0; i < d; ++i) {
        int s = esrc[beg + i];
        float wgt = dinv[s] * dv;
        if (lane < N_CLASSES)
            val = fmaf(h2[(size_t)s * N_CLASSES + lane], wgt, val);
    }
    float m = (lane < N_CLASSES) ? val : -INFINITY;
#pragma unroll
    for (int off = 32; off; off >>= 1) m = fmaxf(m, __shfl_xor(m, off, 64));
    float e = (lane < N_CLASSES) ? expf(val - m) : 0.f;
    float s_ = e;
#pragma unroll
    for (int off = 32; off; off >>= 1) s_ += __shfl_xor(s_, off, 64);
    if (lane < N_CLASSES)
        out[(size_t)v * N_CLASSES + lane] = val - m - logf(s_);
}

// ---------------- launch ----------------

extern "C" void kernel_launch(void* const* d_in, const int* in_sizes, int n_in,
                              void* d_out, int out_size, void* d_ws, size_t ws_size,
                              hipStream_t stream) {
    const float* x  = (const float*)d_in[0];
    const int*   ei = (const int*)d_in[1];
    const float* W1 = (const float*)d_in[2];
    const float* b1 = (const float*)d_in[3];
    const float* W2 = (const float*)d_in[4];
    const float* b2 = (const float*)d_in[5];
    const int* src = ei;
    const int* dst = ei + N_EDGES;
    float* out = (float*)d_out;

    char* ws = (char*)d_ws;
    size_t off = 0;
    auto alloc = [&](size_t bytes) {
        void* p = ws + off;
        off += (bytes + 255) & ~(size_t)255;
        return p;
    };
    int*   deg    = (int*)alloc((size_t)N_NODES * 4);
    float* dinv   = (float*)alloc((size_t)N_NODES * 4);
    int*   rowptr = (int*)alloc((size_t)NB_NODES * 256 * 4);  // scan writes full blocks
    int*   bsum   = (int*)alloc((size_t)NB_NODES * 4);
    int*   cursor = (int*)alloc((size_t)N_NODES * 4);
    int*   esrc   = (int*)alloc((size_t)N_EDGES * 4);
    float* h1     = (float*)alloc((size_t)N_NODES * HIDDEN * 4);
    float* hag    = (float*)alloc((size_t)N_NODES * HIDDEN * 4);
    float* h2     = (float*)alloc((size_t)N_NODES * N_CLASSES * 4);

    hipMemsetAsync(deg, 0, (size_t)N_NODES * 4, stream);
    hipMemsetAsync(cursor, 0, (size_t)N_NODES * 4, stream);

    count_deg<<<(N_EDGES + 255) / 256, 256, 0, stream>>>(dst, deg);
    calc_dinv<<<NB_NODES, 256, 0, stream>>>(deg, dinv);
    scan1<<<NB_NODES, 256, 0, stream>>>(deg, rowptr, bsum);
    scan2<<<1, 256, 0, stream>>>(bsum);
    scan3<<<NB_NODES, 256, 0, stream>>>(rowptr, deg, bsum);
    fill_csr<<<(N_EDGES + 255) / 256, 256, 0, stream>>>(src, dst, rowptr, cursor, esrc);

    gemm1<<<N_NODES / 8, 256, 0, stream>>>(x, W1, h1);
    agg1_gather<<<(N_NODES + 3) / 4, 256, 0, stream>>>(rowptr, deg, esrc, dinv, h1, b1, hag);
    gemm2<<<(N_NODES + 3) / 4, 256, 0, stream>>>(hag, W2, h2);
    agg2_lsm<<<(N_NODES + 3) / 4, 256, 0, stream>>>(rowptr, deg, esrc, dinv, h2, b2, out);
}

// Round 3
// 329.485 us; speedup vs baseline: 2.6814x; 1.4058x over previous
//
#include <hip/hip_runtime.h>
#include <cstdint>

#define N_NODES 50000
#define N_EDGES 800000
#define N_FEAT 256
#define HIDDEN 128
#define N_CLASSES 40
#define NB_NODES ((N_NODES + 255) / 256)   // 196 blocks for node-sized scans
#define ROWS_PAD 50048                      // 782 * 64

typedef __attribute__((ext_vector_type(8))) short bf16x8;
typedef __attribute__((ext_vector_type(4))) float f32x4;

__device__ inline ushort f2bf(float f) {
    union { float f; uint u; } v; v.f = f;
    uint u = v.u;
    u += 0x7fff + ((u >> 16) & 1);   // round-to-nearest-even
    return (ushort)(u >> 16);
}
__device__ inline float bflo(uint u) {
    union { uint u; float f; } v; v.u = u << 16; return v.f;
}
__device__ inline float bfhi(uint u) {
    union { uint u; float f; } v; v.u = u & 0xffff0000u; return v.f;
}

// ---------------- degree / dinv ----------------

__global__ void count_deg(const int* __restrict__ dst, int* __restrict__ deg) {
    int e = blockIdx.x * 256 + threadIdx.x;
    if (e < N_EDGES) atomicAdd(&deg[dst[e]], 1);
}

__global__ void calc_dinv(const int* __restrict__ deg, float* __restrict__ dinv) {
    int i = blockIdx.x * 256 + threadIdx.x;
    if (i < N_NODES) dinv[i] = rsqrtf((float)(deg[i] + 1));  // +1 self-loop
}

// ---------------- exclusive scan of deg -> rowptr ----------------

__global__ void scan1(const int* __restrict__ deg, int* __restrict__ incl,
                      int* __restrict__ bsum) {
    __shared__ int s[256];
    int i = blockIdx.x * 256 + threadIdx.x;
    int v = (i < N_NODES) ? deg[i] : 0;
    s[threadIdx.x] = v;
    __syncthreads();
    for (int off = 1; off < 256; off <<= 1) {
        int t2 = 0;
        if (threadIdx.x >= off) t2 = s[threadIdx.x - off];
        __syncthreads();
        s[threadIdx.x] += t2;
        __syncthreads();
    }
    incl[i] = s[threadIdx.x];
    if (threadIdx.x == 255) bsum[blockIdx.x] = s[255];
}

__global__ void scan2(int* __restrict__ bsum) {
    __shared__ int s[256];
    int t = threadIdx.x;
    s[t] = (t < NB_NODES) ? bsum[t] : 0;
    __syncthreads();
    for (int off = 1; off < 256; off <<= 1) {
        int t2 = 0;
        if (t >= off) t2 = s[t - off];
        __syncthreads();
        s[t] += t2;
        __syncthreads();
    }
    if (t < NB_NODES) bsum[t] = s[t];
}

__global__ void scan3(int* __restrict__ incl, const int* __restrict__ deg,
                      const int* __restrict__ bsum) {
    int i = blockIdx.x * 256 + threadIdx.x;
    if (i >= N_NODES) return;
    int base = (blockIdx.x > 0) ? bsum[blockIdx.x - 1] : 0;
    incl[i] = incl[i] - deg[i] + base;
}

// ---------------- CSR fill ----------------

__global__ void fill_csr(const int* __restrict__ src, const int* __restrict__ dst,
                         const int* __restrict__ rowptr, int* __restrict__ cursor,
                         int* __restrict__ esrc) {
    int e = blockIdx.x * 256 + threadIdx.x;
    if (e >= N_EDGES) return;
    int d = dst[e];
    int p = rowptr[d] + atomicAdd(&cursor[d], 1);
    esrc[p] = src[e];
}

// ---------------- weight repack into MFMA B-fragment order (bf16) ----------------
// Bp[((nt*KT + kt)*64 + lane)*8 + j] = W[k][n], k = kt*32 + (lane>>4)*8 + j, n = nt*16 + (lane&15)

__global__ void repack_W1(const float* __restrict__ W, ushort* __restrict__ Bp) {
    int idx = blockIdx.x * 256 + threadIdx.x;          // 8 nt * 8 kt * 64 * 8 = 32768
    int j = idx & 7, lane = (idx >> 3) & 63, kt = (idx >> 9) & 7, nt = idx >> 12;
    int k = kt * 32 + (lane >> 4) * 8 + j;
    int n = nt * 16 + (lane & 15);
    Bp[idx] = f2bf(W[k * HIDDEN + n]);
}

__global__ void repack_W2(const float* __restrict__ W, ushort* __restrict__ Bp) {
    int idx = blockIdx.x * 256 + threadIdx.x;          // 3 nt * 4 kt * 64 * 8 = 6144
    if (idx >= 6144) return;
    int j = idx & 7, lane = (idx >> 3) & 63, kt = (idx >> 9) & 3, nt = idx >> 11;
    int k = kt * 32 + (lane >> 4) * 8 + j;
    int n = nt * 16 + (lane & 15);
    Bp[idx] = (n < N_CLASSES) ? f2bf(W[k * N_CLASSES + n]) : (ushort)0;
}

// ---------------- GEMM1: h1b[N,128] = bf16(x[N,256]) @ W1  (MFMA) ----------------
// 256 thr = 4 waves; block = 64 rows; wave = 16 rows x 128 cols; K = 256.

#define XS_STRIDE 264   // 256 + 8 bf16 pad -> spreads b128 reads over all banks

__global__ __launch_bounds__(256) void gemm1_mfma(const float* __restrict__ x,
                                                  const ushort* __restrict__ Bp,
                                                  ushort* __restrict__ h1b) {
    __shared__ ushort xs[64 * XS_STRIDE];   // 33792 B
    int t = threadIdx.x;
    int row0 = blockIdx.x * 64;
#pragma unroll
    for (int i = 0; i < 16; ++i) {
        int idx = t + i * 256;              // 4096 chunks of 4 floats
        int r = idx >> 6, kg = idx & 63;
        int row = row0 + r;
        float4 v = make_float4(0.f, 0.f, 0.f, 0.f);
        if (row < N_NODES) v = *(const float4*)(x + (size_t)row * N_FEAT + kg * 4);
        ushort4 u;
        u.x = f2bf(v.x); u.y = f2bf(v.y); u.z = f2bf(v.z); u.w = f2bf(v.w);
        *(ushort4*)(&xs[r * XS_STRIDE + kg * 4]) = u;
    }
    __syncthreads();
    int lane = t & 63, w = t >> 6;
    int r = lane & 15, q = lane >> 4;
    f32x4 acc[8] = {};
    for (int kt = 0; kt < 8; ++kt) {
        bf16x8 a = *(const bf16x8*)(&xs[(w * 16 + r) * XS_STRIDE + kt * 32 + q * 8]);
#pragma unroll
        for (int nt = 0; nt < 8; ++nt) {
            bf16x8 b = *(const bf16x8*)(Bp + (((nt * 8 + kt) * 64) + lane) * 8);
            acc[nt] = __builtin_amdgcn_mfma_f32_16x16x32_bf16(a, b, acc[nt], 0, 0, 0);
        }
    }
#pragma unroll
    for (int nt = 0; nt < 8; ++nt) {
        int col = nt * 16 + r;
#pragma unroll
        for (int reg = 0; reg < 4; ++reg) {
            int row = row0 + w * 16 + q * 4 + reg;
            if (row < N_NODES) h1b[(size_t)row * HIDDEN + col] = f2bf(acc[nt][reg]);
        }
    }
}

// ---------------- layer-1 aggregation (bf16 gather, fp32 acc) ----------------
// one wave per node; lane handles feats {2*lane, 2*lane+1}.

__global__ void agg1_g(const int* __restrict__ rowptr, const int* __restrict__ deg,
                       const int* __restrict__ esrc, const float* __restrict__ dinv,
                       const ushort* __restrict__ h1b, const float* __restrict__ b1,
                       ushort* __restrict__ hagb) {
    int w = threadIdx.x >> 6, lane = threadIdx.x & 63;
    int v = blockIdx.x * 4 + w;
    if (v >= N_NODES) return;
    int beg = rowptr[v], d = deg[v];
    float dv = dinv[v];
    uint hv = *(const uint*)(h1b + (size_t)v * HIDDEN + lane * 2);
    float ax = bflo(hv) * dv * dv, ay = bfhi(hv) * dv * dv;
    int e_l = (lane < d) ? esrc[beg + lane] : 0;
    float w_l = (lane < d) ? dinv[e_l] : 0.f;
    int dm = min(d, 64);
    for (int i = 0; i < dm; ++i) {
        int s = __shfl(e_l, i, 64);
        float wgt = __shfl(w_l, i, 64) * dv;
        uint hs = *(const uint*)(h1b + (size_t)s * HIDDEN + lane * 2);
        ax = fmaf(bflo(hs), wgt, ax);
        ay = fmaf(bfhi(hs), wgt, ay);
    }
    for (int i = 64; i < d; ++i) {           // vanishingly rare (deg ~ Poisson(16))
        int s = esrc[beg + i];
        float wgt = dinv[s] * dv;
        uint hs = *(const uint*)(h1b + (size_t)s * HIDDEN + lane * 2);
        ax = fmaf(bflo(hs), wgt, ax);
        ay = fmaf(bfhi(hs), wgt, ay);
    }
    float2 bb = ((const float2*)b1)[lane];
    ax += bb.x; ay += bb.y;
    ax = ax > 0.f ? ax : 0.f;
    ay = ay > 0.f ? ay : 0.f;
    uint o = ((uint)f2bf(ay) << 16) | (uint)f2bf(ax);
    *(uint*)(hagb + (size_t)v * HIDDEN + lane * 2) = o;
}

// ---------------- GEMM2: h2b[N,40] = hagb[N,128] @ W2  (MFMA) ----------------
// A-frags straight from global (16 B/lane); N padded to 48 (3 n-tiles), K=128.

__global__ __launch_bounds__(256) void gemm2_mfma(const ushort* __restrict__ hagb,
                                                  const ushort* __restrict__ Bp,
                                                  ushort* __restrict__ h2b) {
    int t = threadIdx.x;
    int lane = t & 63, w = t >> 6;
    int r = lane & 15, q = lane >> 4;
    int row0 = blockIdx.x * 64;
    int arow = row0 + w * 16 + r;            // rows < ROWS_PAD, buffer padded
    f32x4 acc[3] = {};
    for (int kt = 0; kt < 4; ++kt) {
        bf16x8 a = *(const bf16x8*)(hagb + (size_t)arow * HIDDEN + kt * 32 + q * 8);
#pragma unroll
        for (int nt = 0; nt < 3; ++nt) {
            bf16x8 b = *(const bf16x8*)(Bp + (((nt * 4 + kt) * 64) + lane) * 8);
            acc[nt] = __builtin_amdgcn_mfma_f32_16x16x32_bf16(a, b, acc[nt], 0, 0, 0);
        }
    }
#pragma unroll
    for (int nt = 0; nt < 3; ++nt) {
        int col = nt * 16 + r;
        if (col >= N_CLASSES) continue;
#pragma unroll
        for (int reg = 0; reg < 4; ++reg) {
            int row = row0 + w * 16 + q * 4 + reg;
            if (row < N_NODES) h2b[(size_t)row * N_CLASSES + col] = f2bf(acc[nt][reg]);
        }
    }
}

// ---------------- layer-2 aggregation + bias + log_softmax ----------------
// one wave per node; lanes 0..19 hold feats {2l, 2l+1}.

__global__ void agg2_lsm(const int* __restrict__ rowptr, const int* __restrict__ deg,
                         const int* __restrict__ esrc, const float* __restrict__ dinv,
                         const ushort* __restrict__ h2b, const float* __restrict__ b2,
                         float* __restrict__ out) {
    int w = threadIdx.x >> 6, lane = threadIdx.x & 63;
    int v = blockIdx.x * 4 + w;
    if (v >= N_NODES) return;
    int beg = rowptr[v], d = deg[v];
    float dv = dinv[v];
    float ax = 0.f, ay = 0.f;
    if (lane < 20) {
        uint hv = *(const uint*)(h2b + (size_t)v * N_CLASSES + lane * 2);
        ax = bflo(hv) * dv * dv;
        ay = bfhi(hv) * dv * dv;
    }
    int e_l = (lane < d) ? esrc[beg + lane] : 0;
    float w_l = (lane < d) ? dinv[e_l] : 0.f;
    int dm = min(d, 64);
    for (int i = 0; i < dm; ++i) {
        int s = __shfl(e_l, i, 64);
        float wgt = __shfl(w_l, i, 64) * dv;
        if (lane < 20) {
            uint hs = *(const uint*)(h2b + (size_t)s * N_CLASSES + lane * 2);
            ax = fmaf(bflo(hs), wgt, ax);
            ay = fmaf(bfhi(hs), wgt, ay);
        }
    }
    for (int i = 64; i < d; ++i) {
        int s = esrc[beg + i];
        float wgt = dinv[s] * dv;
        if (lane < 20) {
            uint hs = *(const uint*)(h2b + (size_t)s * N_CLASSES + lane * 2);
            ax = fmaf(bflo(hs), wgt, ax);
            ay = fmaf(bfhi(hs), wgt, ay);
        }
    }
    if (lane < 20) {
        float2 bb = ((const float2*)b2)[lane];
        ax += bb.x; ay += bb.y;
    }
    float m = (lane < 20) ? fmaxf(ax, ay) : -INFINITY;
#pragma unroll
    for (int off = 32; off; off >>= 1) m = fmaxf(m, __shfl_xor(m, off, 64));
    float e = (lane < 20) ? (expf(ax - m) + expf(ay - m)) : 0.f;
#pragma unroll
    for (int off = 32; off; off >>= 1) e += __shfl_xor(e, off, 64);
    float ls = logf(e);
    if (lane < 20) {
        float2 o;
        o.x = ax - m - ls;
        o.y = ay - m - ls;
        ((float2*)(out + (size_t)v * N_CLASSES))[lane] = o;
    }
}

// ---------------- launch ----------------

extern "C" void kernel_launch(void* const* d_in, const int* in_sizes, int n_in,
                              void* d_out, int out_size, void* d_ws, size_t ws_size,
                              hipStream_t stream) {
    const float* x  = (const float*)d_in[0];
    const int*   ei = (const int*)d_in[1];
    const float* W1 = (const float*)d_in[2];
    const float* b1 = (const float*)d_in[3];
    const float* W2 = (const float*)d_in[4];
    const float* b2 = (const float*)d_in[5];
    const int* src = ei;
    const int* dst = ei + N_EDGES;
    float* out = (float*)d_out;

    char* ws = (char*)d_ws;
    size_t off = 0;
    auto alloc = [&](size_t bytes) {
        void* p = ws + off;
        off += (bytes + 255) & ~(size_t)255;
        return p;
    };
    int*    deg    = (int*)alloc((size_t)N_NODES * 4);
    float*  dinv   = (float*)alloc((size_t)N_NODES * 4);
    int*    rowptr = (int*)alloc((size_t)NB_NODES * 256 * 4);
    int*    bsum   = (int*)alloc((size_t)NB_NODES * 4);
    int*    cursor = (int*)alloc((size_t)N_NODES * 4);
    int*    esrc   = (int*)alloc((size_t)N_EDGES * 4);
    ushort* Bp1    = (ushort*)alloc((size_t)32768 * 2);
    ushort* Bp2    = (ushort*)alloc((size_t)6144 * 2);
    ushort* h1b    = (ushort*)alloc((size_t)ROWS_PAD * HIDDEN * 2);
    ushort* hagb   = (ushort*)alloc((size_t)ROWS_PAD * HIDDEN * 2);
    ushort* h2b    = (ushort*)alloc((size_t)ROWS_PAD * N_CLASSES * 2);

    hipMemsetAsync(deg, 0, (size_t)N_NODES * 4, stream);
    hipMemsetAsync(cursor, 0, (size_t)N_NODES * 4, stream);

    repack_W1<<<32768 / 256, 256, 0, stream>>>(W1, Bp1);
    repack_W2<<<24, 256, 0, stream>>>(W2, Bp2);

    count_deg<<<(N_EDGES + 255) / 256, 256, 0, stream>>>(dst, deg);
    calc_dinv<<<NB_NODES, 256, 0, stream>>>(deg, dinv);
    scan1<<<NB_NODES, 256, 0, stream>>>(deg, rowptr, bsum);
    scan2<<<1, 256, 0, stream>>>(bsum);
    scan3<<<NB_NODES, 256, 0, stream>>>(rowptr, deg, bsum);
    fill_csr<<<(N_EDGES + 255) / 256, 256, 0, stream>>>(src, dst, rowptr, cursor, esrc);

    gemm1_mfma<<<ROWS_PAD / 64, 256, 0, stream>>>(x, Bp1, h1b);
    agg1_g<<<(N_NODES + 3) / 4, 256, 0, stream>>>(rowptr, deg, esrc, dinv, h1b, b1, hagb);
    gemm2_mfma<<<ROWS_PAD / 64, 256, 0, stream>>>(hagb, Bp2, h2b);
    agg2_lsm<<<(N_NODES + 3) / 4, 256, 0, stream>>>(rowptr, deg, esrc, dinv, h2b, b2, out);
}

// Round 4
// 267.719 us; speedup vs baseline: 3.3000x; 1.2307x over previous
//
#include <hip/hip_runtime.h>
#include <cstdint>

#define N_NODES 50000
#define N_EDGES 800000
#define N_FEAT 256
#define HIDDEN 128
#define N_CLASSES 40
#define NB_NODES ((N_NODES + 255) / 256)   // 196 blocks for node-sized scans
#define ROWS_PAD 50048                      // 782 * 64
#define H2S 64                              // h2 row stride (ushorts) = 128 B aligned

typedef __attribute__((ext_vector_type(8))) short bf16x8;
typedef __attribute__((ext_vector_type(4))) float f32x4;

__device__ inline ushort f2bf(float f) {
    union { float f; uint u; } v; v.f = f;
    uint u = v.u;
    u += 0x7fff + ((u >> 16) & 1);   // round-to-nearest-even
    return (ushort)(u >> 16);
}
__device__ inline float bflo(uint u) {
    union { uint u; float f; } v; v.u = u << 16; return v.f;
}
__device__ inline float bfhi(uint u) {
    union { uint u; float f; } v; v.u = u & 0xffff0000u; return v.f;
}

// ---------------- degree ----------------

__global__ void count_deg(const int* __restrict__ dst, int* __restrict__ deg) {
    int e = blockIdx.x * 256 + threadIdx.x;
    if (e < N_EDGES) atomicAdd(&deg[dst[e]], 1);
}

// ---------------- scan of deg -> rowptr, fused dinv ----------------

__global__ void scan1(const int* __restrict__ deg, int* __restrict__ incl,
                      int* __restrict__ bsum, float* __restrict__ dinv) {
    __shared__ int s[256];
    int i = blockIdx.x * 256 + threadIdx.x;
    int v = (i < N_NODES) ? deg[i] : 0;
    if (i < N_NODES) dinv[i] = rsqrtf((float)(v + 1));  // +1 self-loop
    s[threadIdx.x] = v;
    __syncthreads();
    for (int off = 1; off < 256; off <<= 1) {
        int t2 = 0;
        if (threadIdx.x >= off) t2 = s[threadIdx.x - off];
        __syncthreads();
        s[threadIdx.x] += t2;
        __syncthreads();
    }
    incl[i] = s[threadIdx.x];
    if (threadIdx.x == 255) bsum[blockIdx.x] = s[255];
}

__global__ void scan2(int* __restrict__ bsum) {
    __shared__ int s[256];
    int t = threadIdx.x;
    s[t] = (t < NB_NODES) ? bsum[t] : 0;
    __syncthreads();
    for (int off = 1; off < 256; off <<= 1) {
        int t2 = 0;
        if (t >= off) t2 = s[t - off];
        __syncthreads();
        s[t] += t2;
        __syncthreads();
    }
    if (t < NB_NODES) bsum[t] = s[t];
}

__global__ void scan3(int* __restrict__ incl, const int* __restrict__ deg,
                      const int* __restrict__ bsum) {
    int i = blockIdx.x * 256 + threadIdx.x;
    if (i >= N_NODES) return;
    int base = (blockIdx.x > 0) ? bsum[blockIdx.x - 1] : 0;
    incl[i] = incl[i] - deg[i] + base;
}

// ---------------- CSR fill ----------------

__global__ void fill_csr(const int* __restrict__ src, const int* __restrict__ dst,
                         const int* __restrict__ rowptr, int* __restrict__ cursor,
                         int* __restrict__ esrc) {
    int e = blockIdx.x * 256 + threadIdx.x;
    if (e >= N_EDGES) return;
    int d = dst[e];
    int p = rowptr[d] + atomicAdd(&cursor[d], 1);
    esrc[p] = src[e];
}

// ---------------- weight repack into MFMA B-fragment order (bf16), both layers ----------------
// Bp[((nt*KT + kt)*64 + lane)*8 + j] = W[k][n], k = kt*32 + (lane>>4)*8 + j, n = nt*16 + (lane&15)

__global__ void repack_W(const float* __restrict__ W1, const float* __restrict__ W2,
                         ushort* __restrict__ Bp1, ushort* __restrict__ Bp2) {
    int idx = blockIdx.x * 256 + threadIdx.x;   // 32768 + 6144 = 38912 = 152 * 256
    if (idx < 32768) {
        int j = idx & 7, lane = (idx >> 3) & 63, kt = (idx >> 9) & 7, nt = idx >> 12;
        int k = kt * 32 + (lane >> 4) * 8 + j;
        int n = nt * 16 + (lane & 15);
        Bp1[idx] = f2bf(W1[k * HIDDEN + n]);
    } else {
        int i2 = idx - 32768;                   // < 6144
        int j = i2 & 7, lane = (i2 >> 3) & 63, kt = (i2 >> 9) & 3, nt = i2 >> 11;
        int k = kt * 32 + (lane >> 4) * 8 + j;
        int n = nt * 16 + (lane & 15);
        Bp2[i2] = (n < N_CLASSES) ? f2bf(W2[k * N_CLASSES + n]) : (ushort)0;
    }
}

// ---------------- GEMM1: h1b[N,128] = bf16(x[N,256]) @ W1  (MFMA) ----------------

#define XS_STRIDE 264   // 256 + 8 bf16 pad

__global__ __launch_bounds__(256) void gemm1_mfma(const float* __restrict__ x,
                                                  const ushort* __restrict__ Bp,
                                                  ushort* __restrict__ h1b) {
    __shared__ ushort xs[64 * XS_STRIDE];   // 33792 B
    int t = threadIdx.x;
    int row0 = blockIdx.x * 64;
#pragma unroll
    for (int i = 0; i < 16; ++i) {
        int idx = t + i * 256;
        int r = idx >> 6, kg = idx & 63;
        int row = row0 + r;
        float4 v = make_float4(0.f, 0.f, 0.f, 0.f);
        if (row < N_NODES) v = *(const float4*)(x + (size_t)row * N_FEAT + kg * 4);
        ushort4 u;
        u.x = f2bf(v.x); u.y = f2bf(v.y); u.z = f2bf(v.z); u.w = f2bf(v.w);
        *(ushort4*)(&xs[r * XS_STRIDE + kg * 4]) = u;
    }
    __syncthreads();
    int lane = t & 63, w = t >> 6;
    int r = lane & 15, q = lane >> 4;
    f32x4 acc[8] = {};
    for (int kt = 0; kt < 8; ++kt) {
        bf16x8 a = *(const bf16x8*)(&xs[(w * 16 + r) * XS_STRIDE + kt * 32 + q * 8]);
#pragma unroll
        for (int nt = 0; nt < 8; ++nt) {
            bf16x8 b = *(const bf16x8*)(Bp + (((nt * 8 + kt) * 64) + lane) * 8);
            acc[nt] = __builtin_amdgcn_mfma_f32_16x16x32_bf16(a, b, acc[nt], 0, 0, 0);
        }
    }
#pragma unroll
    for (int nt = 0; nt < 8; ++nt) {
        int col = nt * 16 + r;
#pragma unroll
        for (int reg = 0; reg < 4; ++reg) {
            int row = row0 + w * 16 + q * 4 + reg;
            if (row < N_NODES) h1b[(size_t)row * HIDDEN + col] = f2bf(acc[nt][reg]);
        }
    }
}

// ---------------- layer-1 aggregation (bf16 gather, fp32 acc, unroll x4) ----------------
// one wave per node; lane handles feats {2*lane, 2*lane+1}.

__global__ void agg1_g(const int* __restrict__ rowptr, const int* __restrict__ deg,
                       const int* __restrict__ esrc, const float* __restrict__ dinv,
                       const ushort* __restrict__ h1b, const float* __restrict__ b1,
                       ushort* __restrict__ hagb) {
    int w = threadIdx.x >> 6, lane = threadIdx.x & 63;
    int v = blockIdx.x * 4 + w;
    if (v >= N_NODES) return;
    int beg = rowptr[v], d = deg[v];
    float dv = dinv[v];
    uint hv = *(const uint*)(h1b + (size_t)v * HIDDEN + lane * 2);
    float ax = bflo(hv) * dv * dv, ay = bfhi(hv) * dv * dv;
    int e_l = (lane < d) ? esrc[beg + lane] : 0;
    float w_l = (lane < d) ? dinv[e_l] : 0.f;
    int dm = min(d, 64);
    int i = 0;
    for (; i + 4 <= dm; i += 4) {
        int s0 = __shfl(e_l, i + 0, 64);
        int s1 = __shfl(e_l, i + 1, 64);
        int s2 = __shfl(e_l, i + 2, 64);
        int s3 = __shfl(e_l, i + 3, 64);
        float g0 = __shfl(w_l, i + 0, 64) * dv;
        float g1 = __shfl(w_l, i + 1, 64) * dv;
        float g2 = __shfl(w_l, i + 2, 64) * dv;
        float g3 = __shfl(w_l, i + 3, 64) * dv;
        uint h0 = *(const uint*)(h1b + (size_t)s0 * HIDDEN + lane * 2);
        uint h1 = *(const uint*)(h1b + (size_t)s1 * HIDDEN + lane * 2);
        uint h2 = *(const uint*)(h1b + (size_t)s2 * HIDDEN + lane * 2);
        uint h3 = *(const uint*)(h1b + (size_t)s3 * HIDDEN + lane * 2);
        ax = fmaf(bflo(h0), g0, ax); ay = fmaf(bfhi(h0), g0, ay);
        ax = fmaf(bflo(h1), g1, ax); ay = fmaf(bfhi(h1), g1, ay);
        ax = fmaf(bflo(h2), g2, ax); ay = fmaf(bfhi(h2), g2, ay);
        ax = fmaf(bflo(h3), g3, ax); ay = fmaf(bfhi(h3), g3, ay);
    }
    for (; i < dm; ++i) {
        int s = __shfl(e_l, i, 64);
        float g = __shfl(w_l, i, 64) * dv;
        uint hs = *(const uint*)(h1b + (size_t)s * HIDDEN + lane * 2);
        ax = fmaf(bflo(hs), g, ax);
        ay = fmaf(bfhi(hs), g, ay);
    }
    for (i = 64; i < d; ++i) {           // vanishingly rare (deg ~ Poisson(16))
        int s = esrc[beg + i];
        float g = dinv[s] * dv;
        uint hs = *(const uint*)(h1b + (size_t)s * HIDDEN + lane * 2);
        ax = fmaf(bflo(hs), g, ax);
        ay = fmaf(bfhi(hs), g, ay);
    }
    float2 bb = ((const float2*)b1)[lane];
    ax += bb.x; ay += bb.y;
    ax = ax > 0.f ? ax : 0.f;
    ay = ay > 0.f ? ay : 0.f;
    uint o = ((uint)f2bf(ay) << 16) | (uint)f2bf(ax);
    *(uint*)(hagb + (size_t)v * HIDDEN + lane * 2) = o;
}

// ---------------- GEMM2: h2b[N,H2S] = hagb[N,128] @ W2  (MFMA, padded rows) ----------------

__global__ __launch_bounds__(256) void gemm2_mfma(const ushort* __restrict__ hagb,
                                                  const ushort* __restrict__ Bp,
                                                  ushort* __restrict__ h2b) {
    int t = threadIdx.x;
    int lane = t & 63, w = t >> 6;
    int r = lane & 15, q = lane >> 4;
    int row0 = blockIdx.x * 64;
    int arow = row0 + w * 16 + r;            // rows < ROWS_PAD, buffer padded
    f32x4 acc[3] = {};
    for (int kt = 0; kt < 4; ++kt) {
        bf16x8 a = *(const bf16x8*)(hagb + (size_t)arow * HIDDEN + kt * 32 + q * 8);
#pragma unroll
        for (int nt = 0; nt < 3; ++nt) {
            bf16x8 b = *(const bf16x8*)(Bp + (((nt * 4 + kt) * 64) + lane) * 8);
            acc[nt] = __builtin_amdgcn_mfma_f32_16x16x32_bf16(a, b, acc[nt], 0, 0, 0);
        }
    }
#pragma unroll
    for (int nt = 0; nt < 3; ++nt) {
        int col = nt * 16 + r;
        if (col >= N_CLASSES) continue;
#pragma unroll
        for (int reg = 0; reg < 4; ++reg) {
            int row = row0 + w * 16 + q * 4 + reg;
            if (row < N_NODES) h2b[(size_t)row * H2S + col] = f2bf(acc[nt][reg]);
        }
    }
}

// ---------------- layer-2 aggregation + bias + log_softmax ----------------
// TWO nodes per wave (one per 32-lane half); lanes l<20 of each half hold {2l,2l+1}.

__global__ void agg2_lsm(const int* __restrict__ rowptr, const int* __restrict__ deg,
                         const int* __restrict__ esrc, const float* __restrict__ dinv,
                         const ushort* __restrict__ h2b, const float* __restrict__ b2,
                         float* __restrict__ out) {
    int t = threadIdx.x;
    int w = t >> 6, lane = t & 63;
    int half = lane >> 5, l = lane & 31;
    int v = blockIdx.x * 8 + w * 2 + half;   // grid chosen so v < N_NODES always
    int beg = rowptr[v], d = deg[v];
    float dv = dinv[v];
    float ax = 0.f, ay = 0.f;
    if (l < 20) {
        uint hv = *(const uint*)(h2b + (size_t)v * H2S + l * 2);
        ax = bflo(hv) * dv * dv;
        ay = bfhi(hv) * dv * dv;
    }
    int e_l = (l < d) ? esrc[beg + l] : 0;
    float w_l = (l < d) ? dinv[e_l] : 0.f;
    int dm = min(d, 32);
    int base = half * 32;
    int i = 0;
    for (; i + 4 <= dm; i += 4) {
        int s0 = __shfl(e_l, base + i + 0, 64);
        int s1 = __shfl(e_l, base + i + 1, 64);
        int s2 = __shfl(e_l, base + i + 2, 64);
        int s3 = __shfl(e_l, base + i + 3, 64);
        float g0 = __shfl(w_l, base + i + 0, 64) * dv;
        float g1 = __shfl(w_l, base + i + 1, 64) * dv;
        float g2 = __shfl(w_l, base + i + 2, 64) * dv;
        float g3 = __shfl(w_l, base + i + 3, 64) * dv;
        if (l < 20) {
            uint h0 = *(const uint*)(h2b + (size_t)s0 * H2S + l * 2);
            uint h1 = *(const uint*)(h2b + (size_t)s1 * H2S + l * 2);
            uint h2 = *(const uint*)(h2b + (size_t)s2 * H2S + l * 2);
            uint h3 = *(const uint*)(h2b + (size_t)s3 * H2S + l * 2);
            ax = fmaf(bflo(h0), g0, ax); ay = fmaf(bfhi(h0), g0, ay);
            ax = fmaf(bflo(h1), g1, ax); ay = fmaf(bfhi(h1), g1, ay);
            ax = fmaf(bflo(h2), g2, ax); ay = fmaf(bfhi(h2), g2, ay);
            ax = fmaf(bflo(h3), g3, ax); ay = fmaf(bfhi(h3), g3, ay);
        }
    }
    for (; i < dm; ++i) {
        int s = __shfl(e_l, base + i, 64);
        float g = __shfl(w_l, base + i, 64) * dv;
        if (l < 20) {
            uint hs = *(const uint*)(h2b + (size_t)s * H2S + l * 2);
            ax = fmaf(bflo(hs), g, ax);
            ay = fmaf(bfhi(hs), g, ay);
        }
    }
    for (i = 32; i < d; ++i) {               // rare tail
        int s = esrc[beg + i];
        float g = dinv[s] * dv;
        if (l < 20) {
            uint hs = *(const uint*)(h2b + (size_t)s * H2S + l * 2);
            ax = fmaf(bflo(hs), g, ax);
            ay = fmaf(bfhi(hs), g, ay);
        }
    }
    if (l < 20) {
        float2 bb = ((const float2*)b2)[l];
        ax += bb.x; ay += bb.y;
    }
    // softmax within 32-lane half
    float m = (l < 20) ? fmaxf(ax, ay) : -INFINITY;
#pragma unroll
    for (int off = 16; off; off >>= 1) m = fmaxf(m, __shfl_xor(m, off, 64));
    float e = (l < 20) ? (expf(ax - m) + expf(ay - m)) : 0.f;
#pragma unroll
    for (int off = 16; off; off >>= 1) e += __shfl_xor(e, off, 64);
    float ls = logf(e);
    if (l < 20) {
        float2 o;
        o.x = ax - m - ls;
        o.y = ay - m - ls;
        ((float2*)(out + (size_t)v * N_CLASSES))[l] = o;
    }
}

// ---------------- launch ----------------

extern "C" void kernel_launch(void* const* d_in, const int* in_sizes, int n_in,
                              void* d_out, int out_size, void* d_ws, size_t ws_size,
                              hipStream_t stream) {
    const float* x  = (const float*)d_in[0];
    const int*   ei = (const int*)d_in[1];
    const float* W1 = (const float*)d_in[2];
    const float* b1 = (const float*)d_in[3];
    const float* W2 = (const float*)d_in[4];
    const float* b2 = (const float*)d_in[5];
    const int* src = ei;
    const int* dst = ei + N_EDGES;
    float* out = (float*)d_out;

    char* ws = (char*)d_ws;
    size_t off = 0;
    auto alloc = [&](size_t bytes) {
        void* p = ws + off;
        off += (bytes + 255) & ~(size_t)255;
        return p;
    };
    int*    deg    = (int*)alloc((size_t)N_NODES * 4);      // deg+cursor adjacent: one memset
    int*    cursor = (int*)alloc((size_t)N_NODES * 4);
    float*  dinv   = (float*)alloc((size_t)N_NODES * 4);
    int*    rowptr = (int*)alloc((size_t)NB_NODES * 256 * 4);
    int*    bsum   = (int*)alloc((size_t)NB_NODES * 4);
    int*    esrc   = (int*)alloc((size_t)N_EDGES * 4);
    ushort* Bp1    = (ushort*)alloc((size_t)32768 * 2);
    ushort* Bp2    = (ushort*)alloc((size_t)6144 * 2);
    ushort* h1b    = (ushort*)alloc((size_t)ROWS_PAD * HIDDEN * 2);
    ushort* hagb   = (ushort*)alloc((size_t)ROWS_PAD * HIDDEN * 2);
    ushort* h2b    = (ushort*)alloc((size_t)ROWS_PAD * H2S * 2);

    hipMemsetAsync(deg, 0, (size_t)((char*)dinv - (char*)deg), stream);  // deg + cursor

    repack_W<<<152, 256, 0, stream>>>(W1, W2, Bp1, Bp2);
    count_deg<<<(N_EDGES + 255) / 256, 256, 0, stream>>>(dst, deg);
    scan1<<<NB_NODES, 256, 0, stream>>>(deg, rowptr, bsum, dinv);
    scan2<<<1, 256, 0, stream>>>(bsum);
    scan3<<<NB_NODES, 256, 0, stream>>>(rowptr, deg, bsum);
    fill_csr<<<(N_EDGES + 255) / 256, 256, 0, stream>>>(src, dst, rowptr, cursor, esrc);

    gemm1_mfma<<<ROWS_PAD / 64, 256, 0, stream>>>(x, Bp1, h1b);
    agg1_g<<<(N_NODES + 3) / 4, 256, 0, stream>>>(rowptr, deg, esrc, dinv, h1b, b1, hagb);
    gemm2_mfma<<<ROWS_PAD / 64, 256, 0, stream>>>(hagb, Bp2, h2b);
    agg2_lsm<<<N_NODES / 8, 256, 0, stream>>>(rowptr, deg, esrc, dinv, h2b, b2, out);
}

// Round 5
// 216.683 us; speedup vs baseline: 4.0773x; 1.2355x over previous
//
#include <hip/hip_runtime.h>
#include <cstdint>

#define N_NODES 50000
#define N_EDGES 800000
#define N_FEAT 256
#define HIDDEN 128
#define N_CLASSES 40
#define NB_NODES 196        // ceil(50000/256) blocks for node-sized scans
#define NBUCKET 196         // dst >> 8, dst < 50000
#define EPB 3125            // edges per hist/partition block (256 * 3125 = 800000)
#define ROWS_PAD 50048      // 782 * 64
#define H2S 64              // h2 row stride (ushorts) = 128 B aligned

typedef __attribute__((ext_vector_type(8))) short bf16x8;
typedef __attribute__((ext_vector_type(4))) float f32x4;

__device__ inline ushort f2bf(float f) {
    union { float f; uint u; } v; v.f = f;
    uint u = v.u;
    u += 0x7fff + ((u >> 16) & 1);   // round-to-nearest-even
    return (ushort)(u >> 16);
}
__device__ inline float bflo(uint u) {
    union { uint u; float f; } v; v.u = u << 16; return v.f;
}
__device__ inline float bfhi(uint u) {
    union { uint u; float f; } v; v.u = u & 0xffff0000u; return v.f;
}

// ---------------- 1) per-block bucket histogram ----------------

__global__ void hist_k(const int* __restrict__ dst, int* __restrict__ histT) {
    __shared__ int h[NBUCKET];
    int blk = blockIdx.x, t = threadIdx.x;
    if (t < NBUCKET) h[t] = 0;
    __syncthreads();
    int base = blk * EPB;
    for (int i = t; i < EPB; i += 256)
        atomicAdd(&h[dst[base + i] >> 8], 1);
    __syncthreads();
    if (t < NBUCKET) histT[t * 256 + blk] = h[t];   // bucket-major
}

// ---------------- generic 3-phase exclusive scan ----------------

__global__ void scan_a(const int* __restrict__ in, int* __restrict__ incl,
                       int* __restrict__ bsum, int n) {
    __shared__ int s[256];
    int i = blockIdx.x * 256 + threadIdx.x;
    int v = (i < n) ? in[i] : 0;
    s[threadIdx.x] = v;
    __syncthreads();
    for (int off = 1; off < 256; off <<= 1) {
        int t2 = 0;
        if (threadIdx.x >= off) t2 = s[threadIdx.x - off];
        __syncthreads();
        s[threadIdx.x] += t2;
        __syncthreads();
    }
    incl[i] = s[threadIdx.x];
    if (threadIdx.x == 255) bsum[blockIdx.x] = s[255];
}

__global__ void scan_b(int* __restrict__ bsum, int nb) {
    __shared__ int s[256];
    int t = threadIdx.x;
    s[t] = (t < nb) ? bsum[t] : 0;
    __syncthreads();
    for (int off = 1; off < 256; off <<= 1) {
        int t2 = 0;
        if (t >= off) t2 = s[t - off];
        __syncthreads();
        s[t] += t2;
        __syncthreads();
    }
    if (t < nb) bsum[t] = s[t];
}

__global__ void scan_c(int* __restrict__ incl, const int* __restrict__ in,
                       const int* __restrict__ bsum, int n) {
    int i = blockIdx.x * 256 + threadIdx.x;
    if (i >= n) return;
    int base = (blockIdx.x > 0) ? bsum[blockIdx.x - 1] : 0;
    incl[i] = incl[i] - in[i] + base;   // exclusive
}

// ---------------- 2) partition edges into bucket-grouped ebuf ----------------

__global__ void partition_k(const int* __restrict__ src, const int* __restrict__ dst,
                            const int* __restrict__ poff, uint* __restrict__ ebuf) {
    __shared__ int base[NBUCKET];
    __shared__ int cur[NBUCKET];
    int blk = blockIdx.x, t = threadIdx.x;
    if (t < NBUCKET) { base[t] = poff[t * 256 + blk]; cur[t] = 0; }
    __syncthreads();
    int eb = blk * EPB;
    for (int i = t; i < EPB; i += 256) {
        int d = dst[eb + i], s = src[eb + i];
        int bk = d >> 8;
        int p = base[bk] + atomicAdd(&cur[bk], 1);
        ebuf[p] = ((uint)d << 16) | (uint)s;
    }
}

// ---------------- 3) per-bucket degree + dinv (no global atomics, no memset) ----------------

__global__ void bucket_deg(const uint* __restrict__ ebuf, const int* __restrict__ poff,
                           int* __restrict__ deg, float* __restrict__ dinv) {
    __shared__ int dl[256];
    int b = blockIdx.x, t = threadIdx.x;
    dl[t] = 0;
    __syncthreads();
    int beg = poff[b * 256];
    int end = (b < NBUCKET - 1) ? poff[(b + 1) * 256] : N_EDGES;
    for (int i = beg + t; i < end; i += 256)
        atomicAdd(&dl[(ebuf[i] >> 16) - b * 256], 1);
    __syncthreads();
    int node = b * 256 + t;
    if (node < N_NODES) {
        deg[node] = dl[t];
        dinv[node] = rsqrtf((float)(dl[t] + 1));   // +1 self-loop
    }
}

// ---------------- 4) per-bucket CSR fill (LDS cursors, localized writes) ----------------

__global__ void bucket_fill(const uint* __restrict__ ebuf, const int* __restrict__ poff,
                            const int* __restrict__ rowptr, int* __restrict__ esrc) {
    __shared__ int rp[256];
    __shared__ int cur[256];
    int b = blockIdx.x, t = threadIdx.x;
    int node = b * 256 + t;
    rp[t] = (node < N_NODES) ? rowptr[node] : 0;
    cur[t] = 0;
    __syncthreads();
    int beg = poff[b * 256];
    int end = (b < NBUCKET - 1) ? poff[(b + 1) * 256] : N_EDGES;
    for (int i = beg + t; i < end; i += 256) {
        uint u = ebuf[i];
        int dl = (int)(u >> 16) - b * 256;
        int p = rp[dl] + atomicAdd(&cur[dl], 1);
        esrc[p] = (int)(u & 0xffffu);
    }
}

// ---------------- weight repack into MFMA B-fragment order (bf16), both layers ----------------

__global__ void repack_W(const float* __restrict__ W1, const float* __restrict__ W2,
                         ushort* __restrict__ Bp1, ushort* __restrict__ Bp2) {
    int idx = blockIdx.x * 256 + threadIdx.x;   // 32768 + 6144 = 38912 = 152 * 256
    if (idx < 32768) {
        int j = idx & 7, lane = (idx >> 3) & 63, kt = (idx >> 9) & 7, nt = idx >> 12;
        int k = kt * 32 + (lane >> 4) * 8 + j;
        int n = nt * 16 + (lane & 15);
        Bp1[idx] = f2bf(W1[k * HIDDEN + n]);
    } else {
        int i2 = idx - 32768;                   // < 6144
        int j = i2 & 7, lane = (i2 >> 3) & 63, kt = (i2 >> 9) & 3, nt = i2 >> 11;
        int k = kt * 32 + (lane >> 4) * 8 + j;
        int n = nt * 16 + (lane & 15);
        Bp2[i2] = (n < N_CLASSES) ? f2bf(W2[k * N_CLASSES + n]) : (ushort)0;
    }
}

// ---------------- GEMM1: h1b[N,128] = bf16(x[N,256]) @ W1  (MFMA) ----------------

#define XS_STRIDE 264   // 256 + 8 bf16 pad

__global__ __launch_bounds__(256) void gemm1_mfma(const float* __restrict__ x,
                                                  const ushort* __restrict__ Bp,
                                                  ushort* __restrict__ h1b) {
    __shared__ ushort xs[64 * XS_STRIDE];   // 33792 B
    int t = threadIdx.x;
    int row0 = blockIdx.x * 64;
#pragma unroll
    for (int i = 0; i < 16; ++i) {
        int idx = t + i * 256;
        int r = idx >> 6, kg = idx & 63;
        int row = row0 + r;
        float4 v = make_float4(0.f, 0.f, 0.f, 0.f);
        if (row < N_NODES) v = *(const float4*)(x + (size_t)row * N_FEAT + kg * 4);
        ushort4 u;
        u.x = f2bf(v.x); u.y = f2bf(v.y); u.z = f2bf(v.z); u.w = f2bf(v.w);
        *(ushort4*)(&xs[r * XS_STRIDE + kg * 4]) = u;
    }
    __syncthreads();
    int lane = t & 63, w = t >> 6;
    int r = lane & 15, q = lane >> 4;
    f32x4 acc[8] = {};
    for (int kt = 0; kt < 8; ++kt) {
        bf16x8 a = *(const bf16x8*)(&xs[(w * 16 + r) * XS_STRIDE + kt * 32 + q * 8]);
#pragma unroll
        for (int nt = 0; nt < 8; ++nt) {
            bf16x8 b = *(const bf16x8*)(Bp + (((nt * 8 + kt) * 64) + lane) * 8);
            acc[nt] = __builtin_amdgcn_mfma_f32_16x16x32_bf16(a, b, acc[nt], 0, 0, 0);
        }
    }
#pragma unroll
    for (int nt = 0; nt < 8; ++nt) {
        int col = nt * 16 + r;
#pragma unroll
        for (int reg = 0; reg < 4; ++reg) {
            int row = row0 + w * 16 + q * 4 + reg;
            if (row < N_NODES) h1b[(size_t)row * HIDDEN + col] = f2bf(acc[nt][reg]);
        }
    }
}

// ---------------- layer-1 aggregation (bf16 gather, fp32 acc, unroll x4) ----------------

__global__ void agg1_g(const int* __restrict__ rowptr, const int* __restrict__ deg,
                       const int* __restrict__ esrc, const float* __restrict__ dinv,
                       const ushort* __restrict__ h1b, const float* __restrict__ b1,
                       ushort* __restrict__ hagb) {
    int w = threadIdx.x >> 6, lane = threadIdx.x & 63;
    int v = blockIdx.x * 4 + w;
    if (v >= N_NODES) return;
    int beg = rowptr[v], d = deg[v];
    float dv = dinv[v];
    uint hv = *(const uint*)(h1b + (size_t)v * HIDDEN + lane * 2);
    float ax = bflo(hv) * dv * dv, ay = bfhi(hv) * dv * dv;
    int e_l = (lane < d) ? esrc[beg + lane] : 0;
    float w_l = (lane < d) ? dinv[e_l] : 0.f;
    int dm = min(d, 64);
    int i = 0;
    for (; i + 4 <= dm; i += 4) {
        int s0 = __shfl(e_l, i + 0, 64);
        int s1 = __shfl(e_l, i + 1, 64);
        int s2 = __shfl(e_l, i + 2, 64);
        int s3 = __shfl(e_l, i + 3, 64);
        float g0 = __shfl(w_l, i + 0, 64) * dv;
        float g1 = __shfl(w_l, i + 1, 64) * dv;
        float g2 = __shfl(w_l, i + 2, 64) * dv;
        float g3 = __shfl(w_l, i + 3, 64) * dv;
        uint h0 = *(const uint*)(h1b + (size_t)s0 * HIDDEN + lane * 2);
        uint h1 = *(const uint*)(h1b + (size_t)s1 * HIDDEN + lane * 2);
        uint h2 = *(const uint*)(h1b + (size_t)s2 * HIDDEN + lane * 2);
        uint h3 = *(const uint*)(h1b + (size_t)s3 * HIDDEN + lane * 2);
        ax = fmaf(bflo(h0), g0, ax); ay = fmaf(bfhi(h0), g0, ay);
        ax = fmaf(bflo(h1), g1, ax); ay = fmaf(bfhi(h1), g1, ay);
        ax = fmaf(bflo(h2), g2, ax); ay = fmaf(bfhi(h2), g2, ay);
        ax = fmaf(bflo(h3), g3, ax); ay = fmaf(bfhi(h3), g3, ay);
    }
    for (; i < dm; ++i) {
        int s = __shfl(e_l, i, 64);
        float g = __shfl(w_l, i, 64) * dv;
        uint hs = *(const uint*)(h1b + (size_t)s * HIDDEN + lane * 2);
        ax = fmaf(bflo(hs), g, ax);
        ay = fmaf(bfhi(hs), g, ay);
    }
    for (i = 64; i < d; ++i) {           // rare (deg ~ Poisson(16))
        int s = esrc[beg + i];
        float g = dinv[s] * dv;
        uint hs = *(const uint*)(h1b + (size_t)s * HIDDEN + lane * 2);
        ax = fmaf(bflo(hs), g, ax);
        ay = fmaf(bfhi(hs), g, ay);
    }
    float2 bb = ((const float2*)b1)[lane];
    ax += bb.x; ay += bb.y;
    ax = ax > 0.f ? ax : 0.f;
    ay = ay > 0.f ? ay : 0.f;
    uint o = ((uint)f2bf(ay) << 16) | (uint)f2bf(ax);
    *(uint*)(hagb + (size_t)v * HIDDEN + lane * 2) = o;
}

// ---------------- GEMM2: h2b[N,H2S] = hagb[N,128] @ W2  (MFMA, padded rows) ----------------

__global__ __launch_bounds__(256) void gemm2_mfma(const ushort* __restrict__ hagb,
                                                  const ushort* __restrict__ Bp,
                                                  ushort* __restrict__ h2b) {
    int t = threadIdx.x;
    int lane = t & 63, w = t >> 6;
    int r = lane & 15, q = lane >> 4;
    int row0 = blockIdx.x * 64;
    int arow = row0 + w * 16 + r;            // rows < ROWS_PAD, buffer padded
    f32x4 acc[3] = {};
    for (int kt = 0; kt < 4; ++kt) {
        bf16x8 a = *(const bf16x8*)(hagb + (size_t)arow * HIDDEN + kt * 32 + q * 8);
#pragma unroll
        for (int nt = 0; nt < 3; ++nt) {
            bf16x8 b = *(const bf16x8*)(Bp + (((nt * 4 + kt) * 64) + lane) * 8);
            acc[nt] = __builtin_amdgcn_mfma_f32_16x16x32_bf16(a, b, acc[nt], 0, 0, 0);
        }
    }
#pragma unroll
    for (int nt = 0; nt < 3; ++nt) {
        int col = nt * 16 + r;
        if (col >= N_CLASSES) continue;
#pragma unroll
        for (int reg = 0; reg < 4; ++reg) {
            int row = row0 + w * 16 + q * 4 + reg;
            if (row < N_NODES) h2b[(size_t)row * H2S + col] = f2bf(acc[nt][reg]);
        }
    }
}

// ---------------- layer-2 aggregation + bias + log_softmax (2 nodes/wave) ----------------

__global__ void agg2_lsm(const int* __restrict__ rowptr, const int* __restrict__ deg,
                         const int* __restrict__ esrc, const float* __restrict__ dinv,
                         const ushort* __restrict__ h2b, const float* __restrict__ b2,
                         float* __restrict__ out) {
    int t = threadIdx.x;
    int w = t >> 6, lane = t & 63;
    int half = lane >> 5, l = lane & 31;
    int v = blockIdx.x * 8 + w * 2 + half;   // grid: v < N_NODES always
    int beg = rowptr[v], d = deg[v];
    float dv = dinv[v];
    float ax = 0.f, ay = 0.f;
    if (l < 20) {
        uint hv = *(const uint*)(h2b + (size_t)v * H2S + l * 2);
        ax = bflo(hv) * dv * dv;
        ay = bfhi(hv) * dv * dv;
    }
    int e_l = (l < d) ? esrc[beg + l] : 0;
    float w_l = (l < d) ? dinv[e_l] : 0.f;
    int dm = min(d, 32);
    int base = half * 32;
    int i = 0;
    for (; i + 4 <= dm; i += 4) {
        int s0 = __shfl(e_l, base + i + 0, 64);
        int s1 = __shfl(e_l, base + i + 1, 64);
        int s2 = __shfl(e_l, base + i + 2, 64);
        int s3 = __shfl(e_l, base + i + 3, 64);
        float g0 = __shfl(w_l, base + i + 0, 64) * dv;
        float g1 = __shfl(w_l, base + i + 1, 64) * dv;
        float g2 = __shfl(w_l, base + i + 2, 64) * dv;
        float g3 = __shfl(w_l, base + i + 3, 64) * dv;
        if (l < 20) {
            uint h0 = *(const uint*)(h2b + (size_t)s0 * H2S + l * 2);
            uint h1 = *(const uint*)(h2b + (size_t)s1 * H2S + l * 2);
            uint h2 = *(const uint*)(h2b + (size_t)s2 * H2S + l * 2);
            uint h3 = *(const uint*)(h2b + (size_t)s3 * H2S + l * 2);
            ax = fmaf(bflo(h0), g0, ax); ay = fmaf(bfhi(h0), g0, ay);
            ax = fmaf(bflo(h1), g1, ax); ay = fmaf(bfhi(h1), g1, ay);
            ax = fmaf(bflo(h2), g2, ax); ay = fmaf(bfhi(h2), g2, ay);
            ax = fmaf(bflo(h3), g3, ax); ay = fmaf(bfhi(h3), g3, ay);
        }
    }
    for (; i < dm; ++i) {
        int s = __shfl(e_l, base + i, 64);
        float g = __shfl(w_l, base + i, 64) * dv;
        if (l < 20) {
            uint hs = *(const uint*)(h2b + (size_t)s * H2S + l * 2);
            ax = fmaf(bflo(hs), g, ax);
            ay = fmaf(bfhi(hs), g, ay);
        }
    }
    for (i = 32; i < d; ++i) {               // rare tail
        int s = esrc[beg + i];
        float g = dinv[s] * dv;
        if (l < 20) {
            uint hs = *(const uint*)(h2b + (size_t)s * H2S + l * 2);
            ax = fmaf(bflo(hs), g, ax);
            ay = fmaf(bfhi(hs), g, ay);
        }
    }
    if (l < 20) {
        float2 bb = ((const float2*)b2)[l];
        ax += bb.x; ay += bb.y;
    }
    float m = (l < 20) ? fmaxf(ax, ay) : -INFINITY;
#pragma unroll
    for (int off = 16; off; off >>= 1) m = fmaxf(m, __shfl_xor(m, off, 64));
    float e = (l < 20) ? (expf(ax - m) + expf(ay - m)) : 0.f;
#pragma unroll
    for (int off = 16; off; off >>= 1) e += __shfl_xor(e, off, 64);
    float ls = logf(e);
    if (l < 20) {
        float2 o;
        o.x = ax - m - ls;
        o.y = ay - m - ls;
        ((float2*)(out + (size_t)v * N_CLASSES))[l] = o;
    }
}

// ---------------- launch ----------------

extern "C" void kernel_launch(void* const* d_in, const int* in_sizes, int n_in,
                              void* d_out, int out_size, void* d_ws, size_t ws_size,
                              hipStream_t stream) {
    const float* x  = (const float*)d_in[0];
    const int*   ei = (const int*)d_in[1];
    const float* W1 = (const float*)d_in[2];
    const float* b1 = (const float*)d_in[3];
    const float* W2 = (const float*)d_in[4];
    const float* b2 = (const float*)d_in[5];
    const int* src = ei;
    const int* dst = ei + N_EDGES;
    float* out = (float*)d_out;

    char* ws = (char*)d_ws;
    size_t off = 0;
    auto alloc = [&](size_t bytes) {
        void* p = ws + off;
        off += (bytes + 255) & ~(size_t)255;
        return p;
    };
    int*    deg    = (int*)alloc((size_t)NB_NODES * 256 * 4);
    float*  dinv   = (float*)alloc((size_t)N_NODES * 4);
    int*    histT  = (int*)alloc((size_t)NBUCKET * 256 * 4);
    int*    poff   = (int*)alloc((size_t)NBUCKET * 256 * 4);   // scanned partition offsets
    int*    rowptr = (int*)alloc((size_t)NB_NODES * 256 * 4);
    int*    bsumA  = (int*)alloc((size_t)256 * 4);
    int*    bsumB  = (int*)alloc((size_t)256 * 4);
    uint*   ebuf   = (uint*)alloc((size_t)N_EDGES * 4);
    int*    esrc   = (int*)alloc((size_t)N_EDGES * 4);
    ushort* Bp1    = (ushort*)alloc((size_t)32768 * 2);
    ushort* Bp2    = (ushort*)alloc((size_t)6144 * 2);
    ushort* h1b    = (ushort*)alloc((size_t)ROWS_PAD * HIDDEN * 2);
    ushort* hagb   = (ushort*)alloc((size_t)ROWS_PAD * HIDDEN * 2);
    ushort* h2b    = (ushort*)alloc((size_t)ROWS_PAD * H2S * 2);

    repack_W<<<152, 256, 0, stream>>>(W1, W2, Bp1, Bp2);

    // --- edge sort pipeline (no global atomics, no memsets) ---
    hist_k<<<256, 256, 0, stream>>>(dst, histT);
    scan_a<<<NBUCKET, 256, 0, stream>>>(histT, poff, bsumA, NBUCKET * 256);
    scan_b<<<1, 256, 0, stream>>>(bsumA, NBUCKET);
    scan_c<<<NBUCKET, 256, 0, stream>>>(poff, histT, bsumA, NBUCKET * 256);
    partition_k<<<256, 256, 0, stream>>>(src, dst, poff, ebuf);
    bucket_deg<<<NBUCKET, 256, 0, stream>>>(ebuf, poff, deg, dinv);
    scan_a<<<NB_NODES, 256, 0, stream>>>(deg, rowptr, bsumB, N_NODES);
    scan_b<<<1, 256, 0, stream>>>(bsumB, NB_NODES);
    scan_c<<<NB_NODES, 256, 0, stream>>>(rowptr, deg, bsumB, N_NODES);
    bucket_fill<<<NBUCKET, 256, 0, stream>>>(ebuf, poff, rowptr, esrc);

    // --- model ---
    gemm1_mfma<<<ROWS_PAD / 64, 256, 0, stream>>>(x, Bp1, h1b);
    agg1_g<<<(N_NODES + 3) / 4, 256, 0, stream>>>(rowptr, deg, esrc, dinv, h1b, b1, hagb);
    gemm2_mfma<<<ROWS_PAD / 64, 256, 0, stream>>>(hagb, Bp2, h2b);
    agg2_lsm<<<N_NODES / 8, 256, 0, stream>>>(rowptr, deg, esrc, dinv, h2b, b2, out);
}